// Round 2
// baseline (419.240 us; speedup 1.0000x reference)
//
#include <hip/hip_runtime.h>

#define BB 128
#define TT 512
#define CC 128

typedef short short8 __attribute__((ext_vector_type(8)));
typedef float f32x4  __attribute__((ext_vector_type(4)));
typedef unsigned u32x4 __attribute__((ext_vector_type(4)));
typedef unsigned u32x2 __attribute__((ext_vector_type(2)));

__device__ __forceinline__ unsigned pk_trunc(float a, float b) {
    // lo16 = trunc-bf16(a), hi16 = trunc-bf16(b); single v_perm
    return __builtin_amdgcn_perm(__float_as_uint(a), __float_as_uint(b), 0x03020706u);
}
__device__ __forceinline__ unsigned short f2bf(float f) {   // RNE (A setup only)
    unsigned u = __float_as_uint(f);
    u += 0x7fffu + ((u >> 16) & 1u);
    return (unsigned short)(u >> 16);
}
__device__ __forceinline__ float lo16f(unsigned u) { return __uint_as_float(u << 16); }
__device__ __forceinline__ float hi16f(unsigned u) { return __uint_as_float(u & 0xffff0000u); }

#define MFMA16(A, B, C) __builtin_amdgcn_mfma_f32_16x16x32_bf16((A), (B), (C), 0, 0, 0)

// ---------------------------------------------------------------------------
// 512 threads (8 waves) per block.
// Blocks 0..3  : TWO independent scan chains per block (2 waves/SIMD TLP).
//                Chain h = w>>4? no: h = w/4 handles group g = blockIdx*2+h;
//                within a chain, wave wv = w&3 owns output channels 32wv..+31.
//                State exchanged via per-chain 2x4KB double-buffered LDS
//                (column-major, XOR-swizzled, conflict-free ds_read_b128),
//                ONE raw s_barrier per step locksteps both chains; while chain
//                A waits on LDS/MFMA latency, chain B's co-resident wave on the
//                same SIMD issues — latency overlap, issue adds. Per-wave E
//                slices self-loaded with depth-4 register prefetch (no vmcnt
//                drain at barriers); exp stays in f32.
// Blocks 4..131: real-path score, 8 waves x 64 rows; atomicAdd(-score).
// ---------------------------------------------------------------------------
__global__ __launch_bounds__(512, 1) void crf_all(
    const float* __restrict__ y_true, const float* __restrict__ y_pred,
    const float* __restrict__ mask, const float* __restrict__ trans,
    float* __restrict__ out)
{
    __shared__ __align__(16) unsigned sbuf[2][2][1024];  // [chain][buf] 16 KB
    __shared__ float red[2][4][16];

    const int tid  = threadIdx.x;
    const int lane = tid & 63;
    const int w    = tid >> 6;
    const int bq   = lane & 15;
    const int q    = lane >> 4;

    if (blockIdx.x >= 4) {
        // ===================== real path (verified core, 8x64) =============
        const int rb  = blockIdx.x - 4;
        const int ts  = w * 64;
        const int te  = min(ts + 64, TT - 1);
        const float* yt_b = y_true + (size_t)rb * TT * CC;
        const float* yp_b = y_pred + (size_t)rb * TT * CC;
        const float* m_b  = mask + (size_t)rb * TT;

        float em = 0.f, tr = 0.f;
        int lprev = 0; float mprev = 0.f;
        const float* ytr = yt_b + ts * CC;
        const float* ypr = yp_b + ts * CC;
        float cyt0 = ytr[lane], cyt1 = ytr[lane + 64];
        float cyp0 = ypr[lane], cyp1 = ypr[lane + 64];
        float cm = m_b[ts];
        for (int t = ts; t <= te; ++t) {
            float nyt0 = 0.f, nyt1 = 0.f, nyp0 = 0.f, nyp1 = 0.f, nm = 0.f;
            if (t < te) {
                const float* ytn = yt_b + (t + 1) * CC;
                const float* ypn = yp_b + (t + 1) * CC;
                nyt0 = ytn[lane]; nyt1 = ytn[lane + 64];
                nyp0 = ypn[lane]; nyp1 = ypn[lane + 64];
                nm = m_b[t + 1];
            }
            unsigned long long b0 = __ballot(cyt0 > 0.5f);
            unsigned long long b1 = __ballot(cyt1 > 0.5f);
            int l = b0 ? (__ffsll(b0) - 1) : (64 + __ffsll(b1) - 1);
            float v0 = __shfl(cyp0, l & 63);
            float v1 = __shfl(cyp1, l & 63);
            float v  = (l < 64) ? v0 : v1;
            if (lane == 0) {
                if (t < ts + 64) em += cm * cm * v;
                if (t > ts)      tr += mprev * cm * trans[lprev * CC + l];
            }
            lprev = l; mprev = cm;
            cyt0 = nyt0; cyt1 = nyt1; cyp0 = nyp0; cyp1 = nyp1; cm = nm;
        }
        if (lane == 0) atomicAdd(&out[rb], -(em + tr));
        return;
    }

    // ========================== scan blocks ==========================
    const int h  = w >> 2;                   // chain 0/1
    const int wv = w & 3;                    // wave role within chain
    const int g  = blockIdx.x * 2 + h;       // group 0..7
    const float* yb   = y_pred + (size_t)(g * 16 + bq) * TT * CC;
    const float* mrow = mask + (size_t)(g * 16 + bq) * TT;
    const int ch0 = 32 * wv + 4 * q;         // first channel of this lane's E slice

    // Issue t=0 + t=1..4 global loads early; compute A-frags under them.
    const float4 i0 = *(const float4*)(yb + ch0);
    const float4 i1 = *(const float4*)(yb + ch0 + 16);
    const float  m0 = mrow[0];
    float4 pfa[4], pfb[4]; float pfm[4];
    #pragma unroll
    for (int p = 0; p < 4; ++p) {
        pfa[p] = *(const float4*)(yb + (size_t)(1 + p) * CC + ch0);
        pfb[p] = *(const float4*)(yb + (size_t)(1 + p) * CC + ch0 + 16);
        pfm[p] = mrow[1 + p];
    }

    // A-frags: tile nt = 2wv+n2 covers output rows j = nt*16 + m (m = lane&15).
    // A[m][k] = expT[i=k][j], i = kt*32 + q*8 + e (k-layout verified earlier).
    short8 Af[2][4];
    #pragma unroll
    for (int n2 = 0; n2 < 2; ++n2) {
        const int j = (2 * wv + n2) * 16 + bq;
        #pragma unroll
        for (int kt = 0; kt < 4; ++kt) {
            #pragma unroll
            for (int e = 0; e < 8; ++e)
                Af[n2][kt][e] = (short)f2bf(__expf(trans[(kt * 32 + q * 8 + e) * CC + j]));
        }
    }

    // LDS state addressing: col bq at 64 words, pair P stored at word (P ^ swz),
    // swz = (bq&7)<<2.  Reads (4 x b128): exactly 8 accesses/bank (conflict-free).
    const int swz = (bq & 7) << 2;
    const int rw0 = bq * 64 + (( 0 + 4 * q) ^ swz);
    const int rw1 = bq * 64 + ((16 + 4 * q) ^ swz);
    const int rw2 = bq * 64 + ((32 + 4 * q) ^ swz);
    const int rw3 = bq * 64 + ((48 + 4 * q) ^ swz);
    const int ww0 = bq * 64 + ((16 * wv + 2 * q) ^ swz);      // pairs 16wv+2q, +1
    const int ww1 = bq * 64 + ((16 * wv + 8 + 2 * q) ^ swz);  // pairs 16wv+8+2q, +1

    // t=0 init: state = exp(y_pred[:,0,:] * m0) (live always at t=0)
    {
        unsigned p0 = pk_trunc(__expf(i0.x * m0), __expf(i0.y * m0));
        unsigned p1 = pk_trunc(__expf(i0.z * m0), __expf(i0.w * m0));
        unsigned p2 = pk_trunc(__expf(i1.x * m0), __expf(i1.y * m0));
        unsigned p3 = pk_trunc(__expf(i1.z * m0), __expf(i1.w * m0));
        u32x2 a; a[0] = p0; a[1] = p1;
        u32x2 b; b[0] = p2; b[1] = p3;
        *(u32x2*)(&sbuf[h][0][0] + ww0) = a;
        *(u32x2*)(&sbuf[h][0][0] + ww1) = b;
    }
    asm volatile("s_waitcnt lgkmcnt(0)" ::: "memory");
    __builtin_amdgcn_s_barrier();
    asm volatile("" ::: "memory");

    float lacc = 0.f;

    // One scan step. rpar = (t-1)&1 (read buffer), writes rpar^1.
    // ap: renorm step (t == 1 mod 4): pend = 1/state[0][col], lacc += log.
    // tn >= 0: prefetch E(tn) into slot p.
    auto dostep = [&](const int p, const int rpar, const bool ap, const int tn) {
        const unsigned* sb = &sbuf[h][rpar][0];
        unsigned* sw = &sbuf[h][rpar ^ 1][0];
        u32x4 B0 = *(const u32x4*)(sb + rw0);
        u32x4 B1 = *(const u32x4*)(sb + rw1);
        u32x4 B2 = *(const u32x4*)(sb + rw2);
        u32x4 B3 = *(const u32x4*)(sb + rw3);
        float pend = 1.f;
        if (ap) {
            float bc = __shfl(lo16f(B0[0]), bq, 64);   // state[0][col] from q=0 lanes
            pend = __builtin_amdgcn_rcpf(bc);
            lacc += __logf(bc);
        }
        union { u32x4 u; short8 s; } c0, c1, c2, c3;
        c0.u = B0; c1.u = B1; c2.u = B2; c3.u = B3;
        f32x4 a0 = {0.f, 0.f, 0.f, 0.f}, a1 = {0.f, 0.f, 0.f, 0.f};
        a0 = MFMA16(Af[0][0], c0.s, a0); a0 = MFMA16(Af[0][1], c1.s, a0);
        a0 = MFMA16(Af[0][2], c2.s, a0); a0 = MFMA16(Af[0][3], c3.s, a0);
        a1 = MFMA16(Af[1][0], c0.s, a1); a1 = MFMA16(Af[1][1], c1.s, a1);
        a1 = MFMA16(Af[1][2], c2.s, a1); a1 = MFMA16(Af[1][3], c3.s, a1);
        const float mm = pfm[p];
        const float4 va = pfa[p], vb = pfb[p];
        float e0 = __expf(va.x * mm), e1 = __expf(va.y * mm);
        float e2 = __expf(va.z * mm), e3 = __expf(va.w * mm);
        float f0 = __expf(vb.x * mm), f1 = __expf(vb.y * mm);
        float f2 = __expf(vb.z * mm), f3 = __expf(vb.w * mm);
        float v0 = a0[0] * e0, v1 = a0[1] * e1, v2 = a0[2] * e2, v3 = a0[3] * e3;
        float u0 = a1[0] * f0, u1 = a1[1] * f1, u2 = a1[2] * f2, u3 = a1[3] * f3;
        if (ap) {
            v0 *= pend; v1 *= pend; v2 *= pend; v3 *= pend;
            u0 *= pend; u1 *= pend; u2 *= pend; u3 *= pend;
        }
        unsigned n0 = pk_trunc(v0, v1), n1 = pk_trunc(v2, v3);
        unsigned n2 = pk_trunc(u0, u1), n3 = pk_trunc(u2, u3);
        if (__ballot(mm <= 0.f)) {              // rare keep-old (never at runtime)
            u32x2 o0 = *(const u32x2*)(sb + ww0);
            u32x2 o1 = *(const u32x2*)(sb + ww1);
            unsigned k0 = pk_trunc(lo16f(o0[0]) * pend, hi16f(o0[0]) * pend);
            unsigned k1 = pk_trunc(lo16f(o0[1]) * pend, hi16f(o0[1]) * pend);
            unsigned k2 = pk_trunc(lo16f(o1[0]) * pend, hi16f(o1[0]) * pend);
            unsigned k3 = pk_trunc(lo16f(o1[1]) * pend, hi16f(o1[1]) * pend);
            const bool kk = (mm <= 0.f);
            n0 = kk ? k0 : n0; n1 = kk ? k1 : n1;
            n2 = kk ? k2 : n2; n3 = kk ? k3 : n3;
        }
        u32x2 wv0; wv0[0] = n0; wv0[1] = n1;
        u32x2 wv1; wv1[0] = n2; wv1[1] = n3;
        *(u32x2*)(sw + ww0) = wv0;
        *(u32x2*)(sw + ww1) = wv1;
        if (tn >= 0) {                          // depth-4 E prefetch, no vmcnt drain
            pfa[p] = *(const float4*)(yb + (size_t)tn * CC + ch0);
            pfb[p] = *(const float4*)(yb + (size_t)tn * CC + ch0 + 16);
            pfm[p] = mrow[tn];
        }
        asm volatile("s_waitcnt lgkmcnt(0)" ::: "memory");   // LDS writes visible
        __builtin_amdgcn_s_barrier();                        // raw: vm stays in flight
        asm volatile("" ::: "memory");
    };

    // steps 1..508 (127 chunks of 4; tt odd -> rpar = p&1)
    for (int tt = 1; tt <= 505; tt += 4) {
        int t4 = tt + 4, t5 = tt + 5, t6 = tt + 6, t7 = tt + 7;
        if (t7 > TT - 1) t7 = TT - 1;           // only tt=505 clamps (512 -> 511)
        dostep(0, 0, true,  t4);
        dostep(1, 1, false, t5);
        dostep(2, 0, false, t6);
        dostep(3, 1, false, t7);
    }
    // steps 509 (renorm), 510
    dostep(0, 0, true,  -1);
    dostep(1, 1, false, -1);

    // -------- step 511: final sum --------
    {
        const unsigned* sb = &sbuf[h][0][0];    // (511-1)&1 == 0
        u32x4 B0 = *(const u32x4*)(sb + rw0);
        u32x4 B1 = *(const u32x4*)(sb + rw1);
        u32x4 B2 = *(const u32x4*)(sb + rw2);
        u32x4 B3 = *(const u32x4*)(sb + rw3);
        union { u32x4 u; short8 s; } c0, c1, c2, c3;
        c0.u = B0; c1.u = B1; c2.u = B2; c3.u = B3;
        f32x4 a0 = {0.f, 0.f, 0.f, 0.f}, a1 = {0.f, 0.f, 0.f, 0.f};
        a0 = MFMA16(Af[0][0], c0.s, a0); a0 = MFMA16(Af[0][1], c1.s, a0);
        a0 = MFMA16(Af[0][2], c2.s, a0); a0 = MFMA16(Af[0][3], c3.s, a0);
        a1 = MFMA16(Af[1][0], c0.s, a1); a1 = MFMA16(Af[1][1], c1.s, a1);
        a1 = MFMA16(Af[1][2], c2.s, a1); a1 = MFMA16(Af[1][3], c3.s, a1);
        const float mm = pfm[2];
        const float4 va = pfa[2], vb = pfb[2];
        float e0 = __expf(va.x * mm), e1 = __expf(va.y * mm);
        float e2 = __expf(va.z * mm), e3 = __expf(va.w * mm);
        float f0 = __expf(vb.x * mm), f1 = __expf(vb.y * mm);
        float f2 = __expf(vb.z * mm), f3 = __expf(vb.w * mm);
        float ssum = a0[0] * e0 + a0[1] * e1 + a0[2] * e2 + a0[3] * e3
                   + a1[0] * f0 + a1[1] * f1 + a1[2] * f2 + a1[3] * f3;
        if (__ballot(mm <= 0.f)) {              // pend == 1 here (511 % 4 == 3)
            u32x2 o0 = *(const u32x2*)(sb + ww0);
            u32x2 o1 = *(const u32x2*)(sb + ww1);
            float os = lo16f(o0[0]) + hi16f(o0[0]) + lo16f(o0[1]) + hi16f(o0[1])
                     + lo16f(o1[0]) + hi16f(o1[0]) + lo16f(o1[1]) + hi16f(o1[1]);
            ssum = (mm <= 0.f) ? os : ssum;
        }
        ssum += __shfl_xor(ssum, 16, 64);
        ssum += __shfl_xor(ssum, 32, 64);
        if (lane < 16) red[h][wv][lane] = ssum;
        asm volatile("s_waitcnt lgkmcnt(0)" ::: "memory");
        __builtin_amdgcn_s_barrier();
        asm volatile("" ::: "memory");
        if (wv == 0 && lane < 16) {
            float tot = red[h][0][lane] + red[h][1][lane]
                      + red[h][2][lane] + red[h][3][lane];
            atomicAdd(&out[g * 16 + lane], __logf(tot) + lacc);
        }
    }
}

// ---------------------------------------------------------------------------
extern "C" void kernel_launch(void* const* d_in, const int* in_sizes, int n_in,
                              void* d_out, int out_size, void* d_ws, size_t ws_size,
                              hipStream_t stream) {
    (void)in_sizes; (void)n_in; (void)out_size; (void)d_ws; (void)ws_size;
    const float* y_true = (const float*)d_in[0];
    const float* y_pred = (const float*)d_in[1];
    const float* mask   = (const float*)d_in[2];
    const float* trans  = (const float*)d_in[3];
    float* out = (float*)d_out;

    hipMemsetAsync(out, 0, BB * sizeof(float), stream);
    crf_all<<<dim3(4 + BB), 512, 0, stream>>>(y_true, y_pred, mask, trans, out);
}

// Round 3
// 352.199 us; speedup vs baseline: 1.1904x; 1.1904x over previous
//
#include <hip/hip_runtime.h>

#define BB 128
#define TT 512
#define CC 128

typedef short short8 __attribute__((ext_vector_type(8)));
typedef float f32x4  __attribute__((ext_vector_type(4)));
typedef unsigned u32x4 __attribute__((ext_vector_type(4)));
typedef unsigned u32x2 __attribute__((ext_vector_type(2)));

__device__ __forceinline__ unsigned pk_trunc(float a, float b) {
    // lo16 = trunc-bf16(a), hi16 = trunc-bf16(b); single v_perm
    return __builtin_amdgcn_perm(__float_as_uint(a), __float_as_uint(b), 0x03020706u);
}
__device__ __forceinline__ unsigned short f2bf(float f) {   // RNE (A setup only)
    unsigned u = __float_as_uint(f);
    u += 0x7fffu + ((u >> 16) & 1u);
    return (unsigned short)(u >> 16);
}
__device__ __forceinline__ float lo16f(unsigned u) { return __uint_as_float(u << 16); }
__device__ __forceinline__ float hi16f(unsigned u) { return __uint_as_float(u & 0xffff0000u); }

#define MFMA16(A, B, C) __builtin_amdgcn_mfma_f32_16x16x32_bf16((A), (B), (C), 0, 0, 0)

// ---------------------------------------------------------------------------
// crf_scan: 8 blocks x 128 threads (2 waves). One chain per block/CU.
// Wave w owns output channels [64w, 64w+64) = 4 MFMA j-tiles, 16 MFMA/step on
// its own SIMD. Per step: issue 4x ds_read_b128 of the full packed state ->
// compute this step's 16 exp(E) from prefetched regs (hides LDS latency) ->
// MFMAs kt-major (first group needs only B0) -> val-mul, pack, 4x ds_write_b64
// -> lgkmcnt(0) -> raw s_barrier (global prefetch stays in flight).
// R2 lesson: per-CU pipes (LDS/VALU/MFMA) saturate; never co-locate chains.
// ---------------------------------------------------------------------------
__global__ __launch_bounds__(128, 1) void crf_scan(
    const float* __restrict__ y_pred, const float* __restrict__ mask,
    const float* __restrict__ trans, float* __restrict__ out)
{
    __shared__ __align__(16) unsigned sbuf[2][1024];   // 8 KB double-buffered state
    __shared__ float red[2][16];

    const int tid  = threadIdx.x;
    const int lane = tid & 63;
    const int w    = tid >> 6;               // 0/1
    const int bq   = lane & 15;
    const int q    = lane >> 4;

    const int g = blockIdx.x;
    const float* yb   = y_pred + (size_t)(g * 16 + bq) * TT * CC;
    const float* mrow = mask + (size_t)(g * 16 + bq) * TT;
    const int ch0 = 64 * w + 4 * q;          // first channel of this lane's E slice

    // t=0 channels + depth-4 prefetch of t=1..4 (issued before A-frag math).
    float4 i4[4];
    #pragma unroll
    for (int c = 0; c < 4; ++c) i4[c] = *(const float4*)(yb + ch0 + 16 * c);
    const float m0 = mrow[0];
    float4 pf[4][4]; float pfm[4];
    #pragma unroll
    for (int p = 0; p < 4; ++p) {
        #pragma unroll
        for (int c = 0; c < 4; ++c)
            pf[p][c] = *(const float4*)(yb + (size_t)(1 + p) * CC + ch0 + 16 * c);
        pfm[p] = mrow[1 + p];
    }

    // A-frags: tile nt covers output rows j = (4w+nt)*16 + bq; k = kt*32+q*8+e.
    short8 Af[4][4];
    #pragma unroll
    for (int nt = 0; nt < 4; ++nt) {
        const int j = (4 * w + nt) * 16 + bq;
        #pragma unroll
        for (int kt = 0; kt < 4; ++kt) {
            #pragma unroll
            for (int e = 0; e < 8; ++e)
                Af[nt][kt][e] = (short)f2bf(__expf(trans[(kt * 32 + q * 8 + e) * CC + j]));
        }
    }

    // LDS layout: col bq at 64 words; pair P at word (P ^ swz), swz = (bq&7)<<2.
    // Reads (4 x b128): 8 words/bank (optimal). Writes (4 x b64): 4 words/bank.
    const int swz = (bq & 7) << 2;
    const int rw0 = bq * 64 + (( 0 + 4 * q) ^ swz);
    const int rw1 = bq * 64 + ((16 + 4 * q) ^ swz);
    const int rw2 = bq * 64 + ((32 + 4 * q) ^ swz);
    const int rw3 = bq * 64 + ((48 + 4 * q) ^ swz);
    int ww[4];
    #pragma unroll
    for (int nt = 0; nt < 4; ++nt)
        ww[nt] = bq * 64 + ((32 * w + 8 * nt + 2 * q) ^ swz);  // pairs for tile nt

    // t=0 init: state = exp(y_pred[:,0,:] * m0); each wave writes its j-slice.
    #pragma unroll
    for (int c = 0; c < 4; ++c) {
        unsigned p0 = pk_trunc(__expf(i4[c].x * m0), __expf(i4[c].y * m0));
        unsigned p1 = pk_trunc(__expf(i4[c].z * m0), __expf(i4[c].w * m0));
        u32x2 a; a[0] = p0; a[1] = p1;
        *(u32x2*)(&sbuf[0][0] + ww[c]) = a;
    }
    asm volatile("s_waitcnt lgkmcnt(0)" ::: "memory");
    __builtin_amdgcn_s_barrier();
    asm volatile("" ::: "memory");

    float lacc = 0.f;

    // One scan step. rpar = (t-1)&1 (read buffer), writes rpar^1.
    // ap: renorm (t == 1 mod 4). tn >= 0: prefetch E(tn) into slot p.
    auto dostep = [&](const int p, const int rpar, const bool ap, const int tn) {
        const unsigned* sb = &sbuf[rpar][0];
        unsigned* sw = &sbuf[rpar ^ 1][0];
        u32x4 B0 = *(const u32x4*)(sb + rw0);
        u32x4 B1 = *(const u32x4*)(sb + rw1);
        u32x4 B2 = *(const u32x4*)(sb + rw2);
        u32x4 B3 = *(const u32x4*)(sb + rw3);
        // E for this step from prefetched regs — VALU runs under LDS latency.
        const float mm = pfm[p];
        float e[4][4];
        #pragma unroll
        for (int c = 0; c < 4; ++c) {
            e[c][0] = __expf(pf[p][c].x * mm); e[c][1] = __expf(pf[p][c].y * mm);
            e[c][2] = __expf(pf[p][c].z * mm); e[c][3] = __expf(pf[p][c].w * mm);
        }
        float pend = 1.f;
        if (ap) {
            float bc = __shfl(lo16f(B0[0]), bq, 64);   // state[0][col] (q=0 lanes)
            pend = __builtin_amdgcn_rcpf(bc);
            lacc += __logf(bc);
        }
        union { u32x4 u; short8 s; } c0, c1, c2, c3;
        c0.u = B0; c1.u = B1; c2.u = B2; c3.u = B3;
        f32x4 acc[4];
        #pragma unroll
        for (int nt = 0; nt < 4; ++nt) { f32x4 z = {0.f,0.f,0.f,0.f}; acc[nt] = z; }
        // kt-major: first MFMA group only needs B0.
        #pragma unroll
        for (int nt = 0; nt < 4; ++nt) acc[nt] = MFMA16(Af[nt][0], c0.s, acc[nt]);
        #pragma unroll
        for (int nt = 0; nt < 4; ++nt) acc[nt] = MFMA16(Af[nt][1], c1.s, acc[nt]);
        #pragma unroll
        for (int nt = 0; nt < 4; ++nt) acc[nt] = MFMA16(Af[nt][2], c2.s, acc[nt]);
        #pragma unroll
        for (int nt = 0; nt < 4; ++nt) acc[nt] = MFMA16(Af[nt][3], c3.s, acc[nt]);
        unsigned nn[4][2];
        #pragma unroll
        for (int nt = 0; nt < 4; ++nt) {
            float v0 = acc[nt][0] * e[nt][0], v1 = acc[nt][1] * e[nt][1];
            float v2 = acc[nt][2] * e[nt][2], v3 = acc[nt][3] * e[nt][3];
            if (ap) { v0 *= pend; v1 *= pend; v2 *= pend; v3 *= pend; }
            nn[nt][0] = pk_trunc(v0, v1);
            nn[nt][1] = pk_trunc(v2, v3);
        }
        if (__ballot(mm <= 0.f)) {              // rare keep-old (never at runtime)
            #pragma unroll
            for (int nt = 0; nt < 4; ++nt) {
                u32x2 o = *(const u32x2*)(sb + ww[nt]);
                unsigned k0 = pk_trunc(lo16f(o[0]) * pend, hi16f(o[0]) * pend);
                unsigned k1 = pk_trunc(lo16f(o[1]) * pend, hi16f(o[1]) * pend);
                const bool kk = (mm <= 0.f);
                nn[nt][0] = kk ? k0 : nn[nt][0];
                nn[nt][1] = kk ? k1 : nn[nt][1];
            }
        }
        #pragma unroll
        for (int nt = 0; nt < 4; ++nt) {
            u32x2 wv2; wv2[0] = nn[nt][0]; wv2[1] = nn[nt][1];
            *(u32x2*)(sw + ww[nt]) = wv2;
        }
        if (tn >= 0) {                          // depth-4 E prefetch, no vmcnt drain
            #pragma unroll
            for (int c = 0; c < 4; ++c)
                pf[p][c] = *(const float4*)(yb + (size_t)tn * CC + ch0 + 16 * c);
            pfm[p] = mrow[tn];
        }
        asm volatile("s_waitcnt lgkmcnt(0)" ::: "memory");   // LDS writes visible
        __builtin_amdgcn_s_barrier();                        // raw: vm stays in flight
        asm volatile("" ::: "memory");
    };

    // steps 1..508 (127 chunks of 4)
    for (int tt = 1; tt <= 505; tt += 4) {
        int t4 = tt + 4, t5 = tt + 5, t6 = tt + 6, t7 = tt + 7;
        if (t7 > TT - 1) t7 = TT - 1;           // only tt=505 clamps (512 -> 511)
        dostep(0, 0, true,  t4);
        dostep(1, 1, false, t5);
        dostep(2, 0, false, t6);
        dostep(3, 1, false, t7);
    }
    // steps 509 (renorm), 510
    dostep(0, 0, true,  -1);
    dostep(1, 1, false, -1);

    // -------- step 511: final partial sum over this wave's 64 channels -------
    {
        const unsigned* sb = &sbuf[0][0];       // (511-1)&1 == 0
        u32x4 B0 = *(const u32x4*)(sb + rw0);
        u32x4 B1 = *(const u32x4*)(sb + rw1);
        u32x4 B2 = *(const u32x4*)(sb + rw2);
        u32x4 B3 = *(const u32x4*)(sb + rw3);
        const float mm = pfm[2];                // slot 2 holds t=511
        float e[4][4];
        #pragma unroll
        for (int c = 0; c < 4; ++c) {
            e[c][0] = __expf(pf[2][c].x * mm); e[c][1] = __expf(pf[2][c].y * mm);
            e[c][2] = __expf(pf[2][c].z * mm); e[c][3] = __expf(pf[2][c].w * mm);
        }
        union { u32x4 u; short8 s; } c0, c1, c2, c3;
        c0.u = B0; c1.u = B1; c2.u = B2; c3.u = B3;
        f32x4 acc[4];
        #pragma unroll
        for (int nt = 0; nt < 4; ++nt) { f32x4 z = {0.f,0.f,0.f,0.f}; acc[nt] = z; }
        #pragma unroll
        for (int nt = 0; nt < 4; ++nt) acc[nt] = MFMA16(Af[nt][0], c0.s, acc[nt]);
        #pragma unroll
        for (int nt = 0; nt < 4; ++nt) acc[nt] = MFMA16(Af[nt][1], c1.s, acc[nt]);
        #pragma unroll
        for (int nt = 0; nt < 4; ++nt) acc[nt] = MFMA16(Af[nt][2], c2.s, acc[nt]);
        #pragma unroll
        for (int nt = 0; nt < 4; ++nt) acc[nt] = MFMA16(Af[nt][3], c3.s, acc[nt]);
        float ssum = 0.f;
        #pragma unroll
        for (int nt = 0; nt < 4; ++nt)
            ssum += acc[nt][0] * e[nt][0] + acc[nt][1] * e[nt][1]
                  + acc[nt][2] * e[nt][2] + acc[nt][3] * e[nt][3];
        if (__ballot(mm <= 0.f)) {              // pend == 1 here (511 % 4 == 3)
            float os = 0.f;
            #pragma unroll
            for (int nt = 0; nt < 4; ++nt) {
                u32x2 o = *(const u32x2*)(sb + ww[nt]);
                os += lo16f(o[0]) + hi16f(o[0]) + lo16f(o[1]) + hi16f(o[1]);
            }
            ssum = (mm <= 0.f) ? os : ssum;
        }
        ssum += __shfl_xor(ssum, 16, 64);
        ssum += __shfl_xor(ssum, 32, 64);
        if (lane < 16) red[w][lane] = ssum;
        asm volatile("s_waitcnt lgkmcnt(0)" ::: "memory");
        __builtin_amdgcn_s_barrier();
        asm volatile("" ::: "memory");
        if (w == 0 && lane < 16) {
            float tot = red[0][lane] + red[1][lane];
            atomicAdd(&out[g * 16 + lane], __logf(tot) + lacc);
        }
    }
}

// ---------------------------------------------------------------------------
// crf_real: 128 blocks x 256 threads (4 waves x 128 rows) — verified core.
// ---------------------------------------------------------------------------
__global__ __launch_bounds__(256, 1) void crf_real(
    const float* __restrict__ y_true, const float* __restrict__ y_pred,
    const float* __restrict__ mask, const float* __restrict__ trans,
    float* __restrict__ out)
{
    const int tid  = threadIdx.x;
    const int lane = tid & 63;
    const int w    = tid >> 6;
    const int rb   = blockIdx.x;
    const int ts   = w * 128;
    const int te   = min(ts + 128, TT - 1);
    const float* yt_b = y_true + (size_t)rb * TT * CC;
    const float* yp_b = y_pred + (size_t)rb * TT * CC;
    const float* m_b  = mask + (size_t)rb * TT;

    float em = 0.f, tr = 0.f;
    int lprev = 0; float mprev = 0.f;
    const float* ytr = yt_b + ts * CC;
    const float* ypr = yp_b + ts * CC;
    float cyt0 = ytr[lane], cyt1 = ytr[lane + 64];
    float cyp0 = ypr[lane], cyp1 = ypr[lane + 64];
    float cm = m_b[ts];
    for (int t = ts; t <= te; ++t) {
        float nyt0 = 0.f, nyt1 = 0.f, nyp0 = 0.f, nyp1 = 0.f, nm = 0.f;
        if (t < te) {
            const float* ytn = yt_b + (t + 1) * CC;
            const float* ypn = yp_b + (t + 1) * CC;
            nyt0 = ytn[lane]; nyt1 = ytn[lane + 64];
            nyp0 = ypn[lane]; nyp1 = ypn[lane + 64];
            nm = m_b[t + 1];
        }
        unsigned long long b0 = __ballot(cyt0 > 0.5f);
        unsigned long long b1 = __ballot(cyt1 > 0.5f);
        int l = b0 ? (__ffsll(b0) - 1) : (64 + __ffsll(b1) - 1);
        float v0 = __shfl(cyp0, l & 63);
        float v1 = __shfl(cyp1, l & 63);
        float v  = (l < 64) ? v0 : v1;
        if (lane == 0) {
            if (t < ts + 128) em += cm * cm * v;
            if (t > ts)       tr += mprev * cm * trans[lprev * CC + l];
        }
        lprev = l; mprev = cm;
        cyt0 = nyt0; cyt1 = nyt1; cyp0 = nyp0; cyp1 = nyp1; cm = nm;
    }
    if (lane == 0) atomicAdd(&out[rb], -(em + tr));
}

// ---------------------------------------------------------------------------
extern "C" void kernel_launch(void* const* d_in, const int* in_sizes, int n_in,
                              void* d_out, int out_size, void* d_ws, size_t ws_size,
                              hipStream_t stream) {
    (void)in_sizes; (void)n_in; (void)out_size; (void)d_ws; (void)ws_size;
    const float* y_true = (const float*)d_in[0];
    const float* y_pred = (const float*)d_in[1];
    const float* mask   = (const float*)d_in[2];
    const float* trans  = (const float*)d_in[3];
    float* out = (float*)d_out;

    hipMemsetAsync(out, 0, BB * sizeof(float), stream);
    crf_scan<<<dim3(8), 128, 0, stream>>>(y_pred, mask, trans, out);
    crf_real<<<dim3(BB), 256, 0, stream>>>(y_true, y_pred, mask, trans, out);
}